// Round 7
// baseline (2718.301 us; speedup 1.0000x reference)
//
#include <hip/hip_runtime.h>

typedef unsigned short USH;
typedef unsigned int u32;
typedef unsigned long long u64;
typedef float v4f __attribute__((ext_vector_type(4)));
typedef __bf16 v8bf __attribute__((ext_vector_type(8)));
typedef u32 v4u __attribute__((ext_vector_type(4)));

#define B_ 64
#define T_ 512
#define E_ 512
#define H_ 1024
#define NSCAN 128

__device__ __forceinline__ USH f2b(float x) {
  union { float f; u32 u; } v; v.f = x;
  u32 r = v.u + 0x7FFFu + ((v.u >> 16) & 1u);
  return (USH)(r >> 16);
}
__device__ __forceinline__ v8bf ldb8(const USH* p) {
  uint4 u = *reinterpret_cast<const uint4*>(p);
  return __builtin_bit_cast(v8bf, u);
}
__device__ __forceinline__ v4f MF(v8bf a, v8bf b, v4f c) {
  return __builtin_amdgcn_mfma_f32_16x16x32_bf16(a, b, c, 0, 0, 0);
}
__device__ __forceinline__ float sigm(float x) { return 1.0f / (1.0f + __expf(-x)); }
__device__ __forceinline__ float tanhx(float x) { return 1.0f - 2.0f / (__expf(2.0f * x) + 1.0f); }

// fully-coherent load (bypass L1+L2): always fresh from L3
__device__ __forceinline__ v4u ldc16(u64 a) {
  v4u d;
  asm volatile("global_load_dwordx4 %0, %1, off sc0 sc1" : "=v"(d) : "v"(a));
  return d;
}
// L2-cacheable coherent-after-probe load (bypass L1 only) -> enables XCD multicast
__device__ __forceinline__ v4u ldl2(u64 a) {
  v4u d;
  asm volatile("global_load_dwordx4 %0, %1, off sc0" : "=v"(d) : "v"(a));
  return d;
}
__device__ __forceinline__ void stc16(u64 a, v4u d) {
  asm volatile("global_store_dwordx4 %0, %1, off sc1" :: "v"(a), "v"(d) : "memory");
}

// ---------------- f32 -> bf16 cast ----------------
__global__ void castk(const float* __restrict__ s, USH* __restrict__ d, int n) {
  int i = (blockIdx.x * 256 + threadIdx.x) * 4;
  if (i >= n) return;
  float4 v = *reinterpret_cast<const float4*>(s + i);
  ushort4 q = make_ushort4(f2b(v.x), f2b(v.y), f2b(v.z), f2b(v.w));
  *reinterpret_cast<ushort4*>(d + i) = q;
}

// ---------------- embedding gather (-> bf16) ----------------
__global__ void gatherk(const int* __restrict__ x, const float* __restrict__ emb, USH* __restrict__ xeb) {
  int r = blockIdx.x;                       // r = b*T + t
  int id = x[r];
  const float4* e = reinterpret_cast<const float4*>(emb + (long)id * E_);
  float4 v = e[threadIdx.x];                // 128 threads * 4 floats = 512
  ushort4 q = make_ushort4(f2b(v.x), f2b(v.y), f2b(v.z), f2b(v.w));
  *reinterpret_cast<ushort4*>(xeb + (long)r * E_ + threadIdx.x * 4) = q;
}

// ---------------- fused persistent kernel ----------------
// blocks 0..127: GRU scan (bg = blk>>6 batch-group of 32, cb = blk&63 -> 16 h-cols).
//   Weights in REGISTERS. Per-step compact h tile in hsC[t][bg][cb] (sentinel 0xFF).
//   Sync: probe dword (uncached) issued a step early; payload read with sc0-only
//   (L2-cacheable -> XCD multicast), sentinel-verified, escalating to uncached on retry.
// blocks 128..255: emissions, pipelined behind the scan via the same sentinel scheme.
__global__ __launch_bounds__(256, 1) void fused(
    const USH* __restrict__ xeb, const USH* __restrict__ wihB, const USH* __restrict__ whhB,
    const float* __restrict__ bih, const float* __restrict__ bhh, char* __restrict__ hsC,
    const USH* __restrict__ fcwB, const float* __restrict__ fcb, float* __restrict__ em)
{
  __shared__ float redS[6144];   // 24KB reduction
  __shared__ USH  trpS[512];     // 1KB h transpose

  const int tid = threadIdx.x;
  const int wv = tid >> 6, ln = tid & 63;
  const int l16 = ln & 15, lq = ln >> 4;
  const v4f z4 = {0.f, 0.f, 0.f, 0.f};

  // purge stale L2 lines (prior replay / poison) before any cacheable coherent read
  if (tid == 0) {
    (void)__hip_atomic_load((const u32*)hsC, __ATOMIC_ACQUIRE, __HIP_MEMORY_SCOPE_SYSTEM);
    (void)__hip_atomic_load((const u32*)hsC, __ATOMIC_ACQUIRE, __HIP_MEMORY_SCOPE_AGENT);
  }
  __syncthreads();

  if (blockIdx.x < NSCAN) {
    // ================= scan role =================
    const int bg = blockIdx.x >> 6, cb = blockIdx.x & 63;
    const int b0 = bg * 32, c0 = cb * 16;

    // weights -> registers (one-time scattered loads)
    v8bf wihf[4][3], whhf[8][3];
    #pragma unroll
    for (int kt = 0; kt < 4; ++kt)
      #pragma unroll
      for (int g = 0; g < 3; ++g)
        wihf[kt][g] = ldb8(wihB + (size_t)(g * H_ + c0 + l16) * E_ + (wv * 16 + kt * 4 + lq) * 8);
    #pragma unroll
    for (int kt = 0; kt < 8; ++kt)
      #pragma unroll
      for (int g = 0; g < 3; ++g)
        whhf[kt][g] = ldb8(whhB + (size_t)(g * H_ + c0 + l16) * H_ + (wv * 32 + kt * 4 + lq) * 8);

    const int cgl = c0 + l16;
    const float bir = bih[cgl], biz = bih[H_ + cgl], bin = bih[2 * H_ + cgl];
    const float bhr = bhh[cgl], bhz = bhh[H_ + cgl], bhn = bhh[2 * H_ + cgl];

    const USH* a1b = xeb + (size_t)(b0 + l16) * (T_ * E_) + wv * 128 + 8 * lq;
    const u64 hC = (u64)(uintptr_t)hsC + (u64)bg * 65536;
    const int lane_off = (wv * 16 + (lq >> 1)) * 1024 + l16 * 32 + (lq & 1) * 16;
    const u64 probe_off = (u64)((wv * 16 + l16) * 1024 + 1020);  // last dword of tile

    float hp0 = 0.f, hp1 = 0.f, hp2 = 0.f, hp3 = 0.f;  // waves 0/1: running h (4 batches/lane)
    v4f* rv = reinterpret_cast<v4f*>(redS);

    // prefetch xe for t=0
    uint4 pf[8];
    #pragma unroll
    for (int kt = 0; kt < 4; ++kt) {
      pf[kt * 2]     = *reinterpret_cast<const uint4*>(a1b + kt * 32);
      pf[kt * 2 + 1] = *reinterpret_cast<const uint4*>(a1b + 16 * (T_ * E_) + kt * 32);
    }
    u32 pr = 0;

    for (int t = 0; t < T_; ++t) {
      v4f acc[8];  // 0/1:R(m0,m1) 2/3:Z 4/5:NI 6/7:NH
      #pragma unroll
      for (int i = 0; i < 8; ++i) acc[i] = z4;

      // ---- phase 1: xe_t @ w_ih^T (regs only) ----
      #pragma unroll
      for (int kt = 0; kt < 4; ++kt) {
        v8bf a0 = __builtin_bit_cast(v8bf, pf[kt * 2]);
        v8bf a1f = __builtin_bit_cast(v8bf, pf[kt * 2 + 1]);
        acc[0] = MF(a0, wihf[kt][0], acc[0]); acc[1] = MF(a1f, wihf[kt][0], acc[1]);
        acc[2] = MF(a0, wihf[kt][1], acc[2]); acc[3] = MF(a1f, wihf[kt][1], acc[3]);
        acc[4] = MF(a0, wihf[kt][2], acc[4]); acc[5] = MF(a1f, wihf[kt][2], acc[5]);
      }

      if (t > 0) {
        const u64 hbase = hC + (u64)(t - 1) * 131072;
        // ---- probe check (probe was issued at end of previous step; uncached) ----
        while (true) {
          asm volatile("s_waitcnt vmcnt(0)" ::: "memory");
          __builtin_amdgcn_sched_barrier(0);
          if (__ballot(pr != 0xFFFFFFFFu) == ~0ull) break;
          asm volatile("global_load_dword %0, %1, off sc0 sc1" : "=v"(pr) : "v"(hbase + probe_off));
        }
        // ---- payload: L2-cacheable first attempt (XCD multicast) ----
        v4u ha[16];
        #pragma unroll
        for (int kt = 0; kt < 8; ++kt) {
          ha[kt * 2]     = ldl2(hbase + lane_off + kt * 2048);
          ha[kt * 2 + 1] = ldl2(hbase + lane_off + kt * 2048 + 512);
        }
        asm volatile("s_waitcnt vmcnt(0)" ::: "memory");
        __builtin_amdgcn_sched_barrier(0);
        bool bad = false;
        #pragma unroll
        for (int f = 0; f < 16; ++f) {
          #pragma unroll
          for (int d = 0; d < 4; ++d) bad |= (ha[f][d] == 0xFFFFFFFFu);
        }
        // rare: tear / cached-sentinel -> escalate to uncached fresh loads
        while (__ballot(bad) != 0ull) {
          __builtin_amdgcn_s_sleep(1);
          #pragma unroll
          for (int kt = 0; kt < 8; ++kt) {
            ha[kt * 2]     = ldc16(hbase + lane_off + kt * 2048);
            ha[kt * 2 + 1] = ldc16(hbase + lane_off + kt * 2048 + 512);
          }
          asm volatile("s_waitcnt vmcnt(0)" ::: "memory");
          __builtin_amdgcn_sched_barrier(0);
          bad = false;
          #pragma unroll
          for (int f = 0; f < 16; ++f) {
            #pragma unroll
            for (int d = 0; d < 4; ++d) bad |= (ha[f][d] == 0xFFFFFFFFu);
          }
        }
        // ---- phase 2: h_{t-1} @ w_hh^T (regs only) ----
        #pragma unroll
        for (int kt = 0; kt < 8; ++kt) {
          v8bf a0 = __builtin_bit_cast(v8bf, ha[kt * 2]);
          v8bf a1f = __builtin_bit_cast(v8bf, ha[kt * 2 + 1]);
          acc[0] = MF(a0, whhf[kt][0], acc[0]); acc[1] = MF(a1f, whhf[kt][0], acc[1]);
          acc[2] = MF(a0, whhf[kt][1], acc[2]); acc[3] = MF(a1f, whhf[kt][1], acc[3]);
          acc[6] = MF(a0, whhf[kt][2], acc[6]); acc[7] = MF(a1f, whhf[kt][2], acc[7]);
        }
      }

      // ---- single-round cross-wave reduction (24KB), 1 sync ----
      if (wv >= 2) {
        #pragma unroll
        for (int f = 0; f < 8; ++f) rv[(wv - 2) * 512 + f * 64 + ln] = acc[f];
      } else if (wv == 0) {
        #pragma unroll
        for (int j = 0; j < 4; ++j) rv[1024 + j * 64 + ln] = acc[2 * j + 1];  // its mm=1 slices
      } else {
        #pragma unroll
        for (int j = 0; j < 4; ++j) rv[1280 + j * 64 + ln] = acc[2 * j];      // its mm=0 slices
      }
      __syncthreads();

      if (wv < 2) {
        v4f m0, m1, m2, m3;
        if (wv == 0) {
          m0 = acc[0]; m1 = acc[2]; m2 = acc[4]; m3 = acc[6];
          #pragma unroll
          for (int w = 0; w < 2; ++w) {
            m0 += rv[w * 512 + 0 * 64 + ln]; m1 += rv[w * 512 + 2 * 64 + ln];
            m2 += rv[w * 512 + 4 * 64 + ln]; m3 += rv[w * 512 + 6 * 64 + ln];
          }
          m0 += rv[1280 + 0 * 64 + ln]; m1 += rv[1280 + 1 * 64 + ln];
          m2 += rv[1280 + 2 * 64 + ln]; m3 += rv[1280 + 3 * 64 + ln];
        } else {
          m0 = acc[1]; m1 = acc[3]; m2 = acc[5]; m3 = acc[7];
          #pragma unroll
          for (int w = 0; w < 2; ++w) {
            m0 += rv[w * 512 + 1 * 64 + ln]; m1 += rv[w * 512 + 3 * 64 + ln];
            m2 += rv[w * 512 + 5 * 64 + ln]; m3 += rv[w * 512 + 7 * 64 + ln];
          }
          m0 += rv[1024 + 0 * 64 + ln]; m1 += rv[1024 + 1 * 64 + ln];
          m2 += rv[1024 + 2 * 64 + ln]; m3 += rv[1024 + 3 * 64 + ln];
        }
        // ---- gates (wave wv owns batch half mm=wv) ----
        #pragma unroll
        for (int r4 = 0; r4 < 4; ++r4) {
          float rg = sigm(m0[r4] + bir + bhr);
          float zg = sigm(m1[r4] + biz + bhz);
          float ng = tanhx(m2[r4] + bin + rg * (m3[r4] + bhn));
          float hprev = (r4 == 0 ? hp0 : r4 == 1 ? hp1 : r4 == 2 ? hp2 : hp3);
          float hn = (1.f - zg) * ng + zg * hprev;
          if (r4 == 0) hp0 = hn; else if (r4 == 1) hp1 = hn; else if (r4 == 2) hp2 = hn; else hp3 = hn;
          trpS[(wv * 16 + lq * 4 + r4) * 16 + l16] = f2b(hn);
        }
        // readback own rows, store half-tile (512B per wave)
        if (ln < 32) {
          v4u hv = *reinterpret_cast<const v4u*>(trpS + wv * 256 + ln * 8);
          stc16(hC + (u64)t * 131072 + (u64)cb * 1024 + (u64)(wv * 512) + (u64)ln * 16, hv);
        }
      }

      // ---- issue NEXT-step probe (h_t readiness), then xe prefetch ----
      {
        const u64 hb = hC + (u64)t * 131072;
        asm volatile("global_load_dword %0, %1, off sc0 sc1" : "=v"(pr) : "v"(hb + probe_off));
        const USH* a1n = a1b + (size_t)(t + 1 < T_ ? t + 1 : t) * E_;
        #pragma unroll
        for (int kt = 0; kt < 4; ++kt) {
          pf[kt * 2]     = *reinterpret_cast<const uint4*>(a1n + kt * 32);
          pf[kt * 2 + 1] = *reinterpret_cast<const uint4*>(a1n + 16 * (T_ * E_) + kt * 32);
        }
      }
    }
  } else {
    // ================= emission role =================
    const int e = blockIdx.x - NSCAN;
    // hoist fc_w fragments
    v8bf fcf[8][4];
    #pragma unroll
    for (int kt = 0; kt < 8; ++kt)
      #pragma unroll
      for (int nt = 0; nt < 4; ++nt)
        fcf[kt][nt] = ldb8(fcwB + (size_t)(nt * 16 + l16) * H_ + wv * 256 + kt * 32 + 8 * lq);
    float bias[4];
    #pragma unroll
    for (int nt = 0; nt < 4; ++nt) bias[nt] = fcb[nt * 16 + l16];

    v4f* rvE = reinterpret_cast<v4f*>(redS);
    for (int i = 0; i < 16; ++i) {
      int tile = i * 128 + e, t = tile >> 2, bq = tile & 3;
      const u64 ab = (u64)(uintptr_t)hsC + (u64)t * 131072 + (u64)(bq >> 1) * 65536
                   + (u64)((bq & 1) * 16 + l16) * 32 + (u64)(wv * 16 + (lq >> 1)) * 1024 + (u64)(lq & 1) * 16;
      v4u ha[8];
      // first attempt cacheable; escalate to uncached on sentinel
      #pragma unroll
      for (int kt = 0; kt < 8; ++kt) ha[kt] = ldl2(ab + kt * 2048);
      asm volatile("s_waitcnt vmcnt(0)" ::: "memory");
      __builtin_amdgcn_sched_barrier(0);
      bool bad = false;
      #pragma unroll
      for (int kt = 0; kt < 8; ++kt) {
        #pragma unroll
        for (int d = 0; d < 4; ++d) bad |= (ha[kt][d] == 0xFFFFFFFFu);
      }
      while (__ballot(bad) != 0ull) {
        __builtin_amdgcn_s_sleep(32);
        #pragma unroll
        for (int kt = 0; kt < 8; ++kt) ha[kt] = ldc16(ab + kt * 2048);
        asm volatile("s_waitcnt vmcnt(0)" ::: "memory");
        __builtin_amdgcn_sched_barrier(0);
        bad = false;
        #pragma unroll
        for (int kt = 0; kt < 8; ++kt) {
          #pragma unroll
          for (int d = 0; d < 4; ++d) bad |= (ha[kt][d] == 0xFFFFFFFFu);
        }
      }
      v4f acc[4];
      #pragma unroll
      for (int nt = 0; nt < 4; ++nt) acc[nt] = z4;
      #pragma unroll
      for (int kt = 0; kt < 8; ++kt) {
        v8bf a = __builtin_bit_cast(v8bf, ha[kt]);
        #pragma unroll
        for (int nt = 0; nt < 4; ++nt) acc[nt] = MF(a, fcf[kt][nt], acc[nt]);
      }
      __syncthreads();
      if (wv != 0) {
        #pragma unroll
        for (int nt = 0; nt < 4; ++nt) rvE[(wv - 1) * 256 + nt * 64 + ln] = acc[nt];
      }
      __syncthreads();
      if (wv == 0) {
        #pragma unroll
        for (int nt = 0; nt < 4; ++nt) {
          v4f s = acc[nt];
          #pragma unroll
          for (int w = 0; w < 3; ++w) s += rvE[w * 256 + nt * 64 + ln];
          int k = nt * 16 + l16;
          #pragma unroll
          for (int r = 0; r < 4; ++r) {
            int b = bq * 16 + lq * 4 + r;
            em[((size_t)b * T_ + t) * 64 + k] = s[r] + bias[nt];
          }
        }
      }
    }
  }
}

// ---------------- CRF NLL per batch element ----------------
__global__ __launch_bounds__(64) void crfk(const float* __restrict__ em, const int* __restrict__ tags,
                                           const float* __restrict__ st, const float* __restrict__ en,
                                           const float* __restrict__ tr, float* __restrict__ res) {
  int b = blockIdx.x, j = threadIdx.x;
  __shared__ float trs[4096];
  for (int i = j; i < 4096; i += 64) trs[i] = tr[i];
  __syncthreads();
  const int* tg = tags + b * T_;
  const float* e = em + (long)b * T_ * 64;
  float np = 0.f;
  for (int t = j; t < T_; t += 64) {
    int ct = tg[t];
    np += e[t * 64 + ct];
    if (t > 0) np += trs[tg[t - 1] * 64 + ct];
  }
  #pragma unroll
  for (int o = 32; o; o >>= 1) np += __shfl_xor(np, o, 64);
  float num = np + st[tg[0]] + en[tg[T_ - 1]];
  float alpha = st[j] + e[j];
  for (int t = 1; t < T_; ++t) {
    float vv[64];
    #pragma unroll
    for (int i = 0; i < 64; ++i) vv[i] = __shfl(alpha, i, 64) + trs[i * 64 + j];
    float mc[4];
    #pragma unroll
    for (int c = 0; c < 4; ++c) {
      mc[c] = vv[c * 16];
      #pragma unroll
      for (int ii = 1; ii < 16; ++ii) mc[c] = fmaxf(mc[c], vv[c * 16 + ii]);
    }
    float M = fmaxf(fmaxf(mc[0], mc[1]), fmaxf(mc[2], mc[3]));
    float sc[4] = {0.f, 0.f, 0.f, 0.f};
    #pragma unroll
    for (int c = 0; c < 4; ++c)
      #pragma unroll
      for (int ii = 0; ii < 16; ++ii) sc[c] += __expf(vv[c * 16 + ii] - M);
    alpha = M + __logf((sc[0] + sc[1]) + (sc[2] + sc[3])) + e[t * 64 + j];
  }
  float v = alpha + en[j];
  float mm = v;
  #pragma unroll
  for (int o = 32; o; o >>= 1) mm = fmaxf(mm, __shfl_xor(mm, o, 64));
  float ss = __expf(v - mm);
  #pragma unroll
  for (int o = 32; o; o >>= 1) ss += __shfl_xor(ss, o, 64);
  if (j == 0) res[b] = (mm + __logf(ss)) - num;
}

__global__ void fin(const float* __restrict__ res, float* __restrict__ out) {
  float v = res[threadIdx.x];
  #pragma unroll
  for (int o = 32; o; o >>= 1) v += __shfl_xor(v, o, 64);
  if (threadIdx.x == 0) out[0] = v;
}

extern "C" void kernel_launch(void* const* d_in, const int* in_sizes, int n_in,
                              void* d_out, int out_size, void* d_ws, size_t ws_size,
                              hipStream_t stream) {
  (void)in_sizes; (void)n_in; (void)out_size;
  const int*   x    = (const int*)d_in[0];
  const int*   tags = (const int*)d_in[1];
  const float* emb  = (const float*)d_in[2];
  const float* wih  = (const float*)d_in[3];
  const float* whh  = (const float*)d_in[4];
  const float* bih  = (const float*)d_in[5];
  const float* bhh  = (const float*)d_in[6];
  const float* fcw  = (const float*)d_in[7];
  const float* fcb  = (const float*)d_in[8];
  const float* str  = (const float*)d_in[9];
  const float* enr  = (const float*)d_in[10];
  const float* trn  = (const float*)d_in[11];

  char* ws = (char*)d_ws;
  USH*   xeb  = (USH*)(ws + 0);           // 33,554,432
  USH*   wihB = (USH*)(ws + 33554432);    //  3,145,728
  USH*   whhB = (USH*)(ws + 36700160);    //  6,291,456
  USH*   fcwB = (USH*)(ws + 42991616);    //    131,072
  char*  hsC  = (char*)(ws + 43122688);   // 67,108,864: [t][group][cb][row][col] compact h stream
  float* em   = (float*)(ws + 110231552); //  8,388,608 ([B][T][64] f32)
  float* res  = (float*)(ws + 118620160); //        256
  if (ws_size < 118620416ull) return;

  // sentinel-fill the h stream (data-is-the-flag); runs every call / every replay
  hipMemsetAsync(hsC, 0xFF, 67108864, stream);

  castk<<<1536, 256, 0, stream>>>(wih, wihB, 3 * H_ * E_);
  castk<<<3072, 256, 0, stream>>>(whh, whhB, 3 * H_ * H_);
  castk<<<64, 256, 0, stream>>>(fcw, fcwB, 64 * H_);
  gatherk<<<B_ * T_, 128, 0, stream>>>(x, emb, xeb);
  fused<<<256, 256, 0, stream>>>(xeb, wihB, whhB, bih, bhh, hsC, fcwB, fcb, em);
  crfk<<<B_, 64, 0, stream>>>(em, tags, str, enr, trn, res);
  fin<<<1, 64, 0, stream>>>(res, (float*)d_out);
}